// Round 10
// baseline (282.242 us; speedup 1.0000x reference)
//
#include <hip/hip_runtime.h>

typedef _Float16 half_t;
typedef _Float16 half4 __attribute__((ext_vector_type(4)));
typedef _Float16 half8 __attribute__((ext_vector_type(8)));
typedef float floatx4 __attribute__((ext_vector_type(4)));

#define HST 264            // LDS row stride in halves: 256 + 8 pad
#define B_ 32
#define T_ 512
#define H_ 256
#define L_ 2048

// ------------------------------------------------------------------
// Fused setup: blocks [0,128) = meta, blocks [128,512) = weight prep
// fp32 -> f16, CHUNK-CONTIGUOUS layout (round-5 proven):
//   chunk c = (pred*4+layer)*16 + nt   (8 KB each, linear for LDS DMA)
//   within chunk: halves [kk*512 + lane*8 .. +7] hold
//   W[kk*32 + (lane>>4)*8 + j][nt*16 + (lane&15)]
// ------------------------------------------------------------------
__global__ __launch_bounds__(256) void setup_kernel(
    const int* __restrict__ dur,
    const float* __restrict__ pitch_t,
    const float* __restrict__ energy_t,
    const float* __restrict__ dur_W,
    const float* __restrict__ pit_W,
    const float* __restrict__ en_W,
    half_t* __restrict__ Wp,
    int* __restrict__ idx_ws,
    int* __restrict__ pi_ws,
    int* __restrict__ ei_ws,
    int* __restrict__ ml_ws,
    float* __restrict__ out4,
    float* __restrict__ out5) {
  __shared__ int cum_l[T_];
  __shared__ int ml_s;
  int bid = blockIdx.x;
  int tid = threadIdx.x;

  if (bid >= 128) {
    // ---- weight prep ----
    int g = (bid - 128) * 256 + tid;          // [0, 98304)
    int lane = g & 63;
    int t = g >> 6;                            // [0, 1536)
    int nt = t & 15;
    int kk = (t >> 4) & 7;
    int layer = (t >> 7) & 3;
    int pred = t >> 9;
    const float* W = (pred == 0 ? dur_W : (pred == 1 ? pit_W : en_W)) + layer * 65536;
    int n = nt * 16 + (lane & 15);
    int k0 = kk * 32 + (lane >> 4) * 8;
    half8 o;
#pragma unroll
    for (int j = 0; j < 8; ++j) o[j] = (half_t)W[(k0 + j) * 256 + n];
    int c = (pred * 4 + layer) * 16 + nt;
    *(half8*)&Wp[(size_t)c * 4096 + kk * 512 + lane * 8] = o;
    return;
  }

  // ---- meta ----
  int b = bid >> 2;
  int chunk = bid & 3;
  if (tid < 64) {
    int l = tid;
    const int* dr = dur + b * T_;
    int v[8];
    int base = l * 8;
#pragma unroll
    for (int j = 0; j < 8; ++j) v[j] = dr[base + j];
#pragma unroll
    for (int j = 1; j < 8; ++j) v[j] += v[j - 1];
    int tot = v[7];
    int inc = tot;
    for (int d = 1; d < 64; d <<= 1) {
      int t = __shfl_up(inc, d);
      if (l >= d) inc += t;
    }
    int excl = inc - tot;
#pragma unroll
    for (int j = 0; j < 8; ++j) cum_l[base + j] = excl + v[j];
    if (l == 63) {
      int mel = min(inc, L_);
      ml_s = mel;
      if (chunk == 0) {
        ml_ws[b] = mel;
        out4[b] = (float)mel;
      }
    }
  }
  __syncthreads();
  int ml = ml_s;
#pragma unroll
  for (int j = 0; j < 2; ++j) {
    int m = chunk * 512 + j * 256 + tid;
    int lo = 0;
#pragma unroll
    for (int sh = 8; sh >= 0; --sh) {
      int c = lo + (1 << sh);
      if (c <= T_ && cum_l[c - 1] <= m) lo = c;
    }
    int idx = min(lo, T_ - 1);
    int g = b * L_ + m;
    idx_ws[g] = idx;
    pi_ws[g] = (int)ceilf(pitch_t[g] * 256.0f);
    ei_ws[g] = (int)ceilf(energy_t[g] * 256.0f);
    out5[g] = (m >= ml) ? 1.0f : 0.0f;
  }
}

// ------------------------------------------------------------------
// Fused 4-layer MLP + head, 4-wave weight-sharing.
// blocks [0,1024): pitch  [1024,2048): energy  [2048,2304): duration.
// Block = 256 threads (4 waves) / 64 rows; wave owns 16 rows
// EXCLUSIVELY (h tile in-place, no h barriers).
// Weights: ONE LDS copy per 16 KB chunk (2 nt tiles) shared by all 4
// waves, staged via global_load_lds (zero VGPR), double-buffered with
// plain __syncthreads (round-5 proven sync). vs round 5:
//   - 4-way sharing: weight L2 traffic 2.36 -> 1.18 GB
//   - 2-nt chunks: half the barrier/drain frequency
//   - bias/head-w loaded BEFORE the STAGE ops (vmcnt is in-order:
//     loading them after would turn their waits into full drains)
//   - head fused into layer-3 (no head pass, no layer-3 tile writes)
// LDS 33.8 (h tile) + 32 (w dbuf) = 65 KB -> 2 blocks/CU, 8 waves/CU.
// VGPR ~110 (hf 32 + w 32 + misc) -> allocator-friendly.
// Pitch-mode staging also emits out0 = xe + pemb + eemb (fused).
// ------------------------------------------------------------------
__device__ __forceinline__ void stage16(const void* g, void* l) {
  __builtin_amdgcn_global_load_lds(
      (const __attribute__((address_space(1))) void*)g,
      (__attribute__((address_space(3))) void*)l, 16, 0, 0);
}

__global__ __launch_bounds__(256) void predictor_kernel(
    const float* __restrict__ x,
    const half_t* __restrict__ Wp,
    const float* __restrict__ dur_b, const float* __restrict__ dur_w, const float* __restrict__ dur_b2,
    const float* __restrict__ pit_b, const float* __restrict__ pit_w, const float* __restrict__ pit_b2,
    const float* __restrict__ en_b,  const float* __restrict__ en_w,  const float* __restrict__ en_b2,
    const int* __restrict__ idx_ws, const int* __restrict__ pi_ws, const int* __restrict__ ei_ws,
    const int* __restrict__ mlw,
    const float* __restrict__ src_seq, const unsigned char* __restrict__ src_mask,
    const float* __restrict__ pemb, const float* __restrict__ eemb,
    float* __restrict__ out0, float* __restrict__ out1,
    float* __restrict__ out2, float* __restrict__ out3) {
  __shared__ half_t hlds[64 * HST];     // 33792 B: h tile
  __shared__ half_t wlds[16384];        // 32 KB: 2 x 16 KB weight chunk buffers

  int bid = blockIdx.x;
  int mode, blk;
  const half_t* W; const float* bias; const float* wh; const float* b2p; float* outp;
  if (bid < 1024)      { mode = 1; blk = bid;        W = Wp + 262144; bias = pit_b; wh = pit_w; b2p = pit_b2; outp = out2; }
  else if (bid < 2048) { mode = 2; blk = bid - 1024; W = Wp + 524288; bias = en_b;  wh = en_w;  b2p = en_b2;  outp = out3; }
  else                 { mode = 0; blk = bid - 2048; W = Wp;          bias = dur_b; wh = dur_w; b2p = dur_b2; outp = out1; }

  int tid = threadIdx.x;
  int wv = tid >> 6, lane = tid & 63;   // 4 waves
  int mi = lane & 15, qi = lane >> 4;
  int wrow0 = wv * 16;                  // wave's exclusive 16 rows
  int brow0 = blk * 64;

  const char* Wb = (const char*)W;      // 16 KB chunk cc at byte offset cc*16384

  // stage 16 KB chunk cc into dbuf bf; wave wv copies its contiguous 4 KB
#define STAGE(cc, bf)                                                        \
  {                                                                          \
    const char* gsrc = Wb + (size_t)(cc) * 16384 + wv * 4096 + lane * 16;    \
    char* ldst = (char*)wlds + (bf) * 32768 + wv * 4096;                     \
    stage16(gsrc,        ldst);                                              \
    stage16(gsrc + 1024, ldst + 1024);                                       \
    stage16(gsrc + 2048, ldst + 2048);                                       \
    stage16(gsrc + 3072, ldst + 3072);                                       \
  }

  // ---- issue chunk 0 stage first: lands under the h staging below ----
  STAGE(0, 0);

  // ---- stage this wave's 16 input rows (f16) into the h tile ----
  if (mode == 0) {
    for (int it = 0; it < 16; ++it) {
      int rl = wrow0 + it;
      const float4 xv = *(const float4*)&x[(size_t)(brow0 + rl) * H_ + lane * 4];
      half4 h4;
      h4[0] = (half_t)xv.x; h4[1] = (half_t)xv.y;
      h4[2] = (half_t)xv.z; h4[3] = (half_t)xv.w;
      *(half4*)&hlds[rl * HST + lane * 4] = h4;
    }
  } else {
    int b = brow0 >> 11;          // 64 | 2048 frames per batch
    int m0 = brow0 & (L_ - 1);
    int ml = mlw[b];
    for (int it = 0; it < 16; ++it) {
      int rl = wrow0 + it;
      int m = m0 + rl;
      int g = b * L_ + m;
      float4 xv = {0.f, 0.f, 0.f, 0.f};
      if (m < ml) {
        int ir = idx_ws[g];
        xv = *(const float4*)&x[((size_t)(b * T_ + ir)) * H_ + lane * 4];
      }
      if (mode == 1) {
        // fused out0 = xe + pemb[pi] + eemb[ei]
        const float4 pv = *(const float4*)&pemb[(size_t)pi_ws[g] * H_ + lane * 4];
        const float4 ev = *(const float4*)&eemb[(size_t)ei_ws[g] * H_ + lane * 4];
        floatx4 o;
        o[0] = xv.x + pv.x + ev.x;
        o[1] = xv.y + pv.y + ev.y;
        o[2] = xv.z + pv.z + ev.z;
        o[3] = xv.w + pv.w + ev.w;
        __builtin_nontemporal_store(o, (floatx4*)&out0[(size_t)g * H_ + lane * 4]);
      }
      half4 h4;
      h4[0] = (half_t)xv.x; h4[1] = (half_t)xv.y;
      h4[2] = (half_t)xv.z; h4[3] = (half_t)xv.w;
      *(half4*)&hlds[rl * HST + lane * 4] = h4;
    }
  }
  __syncthreads();   // h tile ready; chunk 0 landed (full drain, once)

  half8 hf[8];       // h[wrow0+mi][kk*32+qi*8 .. +7]
  float p = 0.f;     // fused-head partial (layer 3)

  // 32 chunks: cc = layer*8 + np, each = 2 nt tiles
#pragma unroll 1
  for (int cc = 0; cc < 32; ++cc) {
    int layer = cc >> 3, np = cc & 7;
    const float* bl = bias + layer * 256;

    // bias / head-w loads FIRST (before STAGE): vmcnt is in-order, so
    // their compiler waits stay counted instead of draining the stages
    float4 bvA = *(const float4*)&bl[(np * 2) * 16 + qi * 4];
    float4 bvB = *(const float4*)&bl[(np * 2 + 1) * 16 + qi * 4];
    float4 hwA = {0.f, 0.f, 0.f, 0.f}, hwB = {0.f, 0.f, 0.f, 0.f};
    if (layer == 3) {
      hwA = *(const float4*)&wh[(np * 2) * 16 + qi * 4];
      hwB = *(const float4*)&wh[(np * 2 + 1) * 16 + qi * 4];
    }

    if (cc < 31) STAGE(cc + 1, (cc + 1) & 1);

    if (np == 0) {
      // (re)load this wave's 16 rows' fragments (32 VGPRs)
#pragma unroll
      for (int kk = 0; kk < 8; ++kk)
        hf[kk] = *(const half8*)&hlds[(wrow0 + mi) * HST + kk * 32 + qi * 8];
    }

    const half_t* wb = &wlds[(cc & 1) * 16384];
    // ---- sub-tile A (nt = np*2) ----
    {
      half8 w[8];
#pragma unroll
      for (int kk = 0; kk < 8; ++kk)
        w[kk] = *(const half8*)&wb[kk * 512 + lane * 8];
      floatx4 acc = {bvA.x, bvA.y, bvA.z, bvA.w};
#pragma unroll
      for (int kk = 0; kk < 8; ++kk)
        acc = __builtin_amdgcn_mfma_f32_16x16x32_f16(w[kk], hf[kk], acc, 0, 0, 0);
      int nt = np * 2;
      if (layer < 3) {
        half4 h4;
        h4[0] = (half_t)fmaxf(acc[0], 0.f); h4[1] = (half_t)fmaxf(acc[1], 0.f);
        h4[2] = (half_t)fmaxf(acc[2], 0.f); h4[3] = (half_t)fmaxf(acc[3], 0.f);
        *(half4*)&hlds[(wrow0 + mi) * HST + nt * 16 + qi * 4] = h4;
      } else {
        p += fmaxf(acc[0], 0.f) * hwA.x + fmaxf(acc[1], 0.f) * hwA.y
           + fmaxf(acc[2], 0.f) * hwA.z + fmaxf(acc[3], 0.f) * hwA.w;
      }
    }
    // ---- sub-tile B (nt = np*2+1) ----
    {
      half8 w[8];
#pragma unroll
      for (int kk = 0; kk < 8; ++kk)
        w[kk] = *(const half8*)&wb[4096 + kk * 512 + lane * 8];
      floatx4 acc = {bvB.x, bvB.y, bvB.z, bvB.w};
#pragma unroll
      for (int kk = 0; kk < 8; ++kk)
        acc = __builtin_amdgcn_mfma_f32_16x16x32_f16(w[kk], hf[kk], acc, 0, 0, 0);
      int nt = np * 2 + 1;
      if (layer < 3) {
        half4 h4;
        h4[0] = (half_t)fmaxf(acc[0], 0.f); h4[1] = (half_t)fmaxf(acc[1], 0.f);
        h4[2] = (half_t)fmaxf(acc[2], 0.f); h4[3] = (half_t)fmaxf(acc[3], 0.f);
        *(half4*)&hlds[(wrow0 + mi) * HST + nt * 16 + qi * 4] = h4;
      } else {
        p += fmaxf(acc[0], 0.f) * hwB.x + fmaxf(acc[1], 0.f) * hwB.y
           + fmaxf(acc[2], 0.f) * hwB.z + fmaxf(acc[3], 0.f) * hwB.w;
      }
    }

    __syncthreads();   // chunk cc consumed by all waves; chunk cc+1 landed
  }

  // ---- head finalize: reduce partials across the 4 qi lanes ----
  p += __shfl_xor(p, 16);
  p += __shfl_xor(p, 32);
  if (qi == 0) {
    int row = brow0 + wrow0 + mi;
    float d = p + b2p[0];
    if (mode == 0) {
      if (src_mask[row]) d = 0.f;
      float s2 = src_seq[(size_t)row * 3 + 2];
      outp[row] = (tanhf(d) + 1.0f) * s2;
    } else {
      int b = row >> 11;
      int m = row & (L_ - 1);
      float v = (m >= mlw[b]) ? 0.f : d;
      outp[row] = (mode == 1) ? fmaxf(v, 0.f) : v;
    }
  }
#undef STAGE
}

extern "C" void kernel_launch(void* const* d_in, const int* in_sizes, int n_in,
                              void* d_out, int out_size, void* d_ws, size_t ws_size,
                              hipStream_t stream) {
  const float* x        = (const float*)d_in[0];
  const float* src_seq  = (const float*)d_in[1];
  const int*   durt     = (const int*)d_in[2];
  const float* pitcht   = (const float*)d_in[3];
  const float* energyt  = (const float*)d_in[4];
  const unsigned char* src_mask = (const unsigned char*)d_in[5];
  const float* dur_W  = (const float*)d_in[7];
  const float* dur_b  = (const float*)d_in[8];
  const float* dur_w  = (const float*)d_in[9];
  const float* dur_b2 = (const float*)d_in[10];
  const float* pit_W  = (const float*)d_in[11];
  const float* pit_b  = (const float*)d_in[12];
  const float* pit_w  = (const float*)d_in[13];
  const float* pit_b2 = (const float*)d_in[14];
  const float* en_W   = (const float*)d_in[15];
  const float* en_b   = (const float*)d_in[16];
  const float* en_w   = (const float*)d_in[17];
  const float* en_b2  = (const float*)d_in[18];
  const float* pemb   = (const float*)d_in[19];
  const float* eemb   = (const float*)d_in[20];

  float* out0 = (float*)d_out;              // [32,2048,256]
  float* out1 = out0 + 16777216;            // [32,512]   log_duration
  float* out2 = out1 + 16384;               // [32,2048]  pitch_prediction
  float* out3 = out2 + 65536;               // [32,2048]  energy_prediction
  float* out4 = out3 + 65536;               // [32]       mel_len (as float)
  float* out5 = out4 + 32;                  // [32,2048]  mel_mask (0/1 float)

  int* idx_ws = (int*)d_ws;                 // 65536 ints
  int* pi_ws  = idx_ws + 65536;             // 65536 ints
  int* ei_ws  = pi_ws + 65536;              // 65536 ints
  int* ml_ws  = ei_ws + 65536;              // 32 ints
  half_t* Wp  = (half_t*)((char*)d_ws + 786560);  // 786432 halves, 16B aligned

  setup_kernel<<<dim3(512), dim3(256), 0, stream>>>(
      durt, pitcht, energyt, dur_W, pit_W, en_W, Wp,
      idx_ws, pi_ws, ei_ws, ml_ws, out4, out5);
  predictor_kernel<<<dim3(2304), dim3(256), 0, stream>>>(
      x, Wp,
      dur_b, dur_w, dur_b2,
      pit_b, pit_w, pit_b2,
      en_b, en_w, en_b2,
      idx_ws, pi_ws, ei_ws, ml_ws, src_seq, src_mask, pemb, eemb,
      out0, out1, out2, out3);
}